// Round 12
// baseline (495.776 us; speedup 1.0000x reference)
//
#include <hip/hip_runtime.h>
#include <hip/hip_bf16.h>

// Problem constants: B=16, D=64, T=256, BD=TD=H=128, H2=64, NRES=2
#define BDT_TOT 262144  // B*D*T

typedef __attribute__((ext_vector_type(8))) short bf16x8;
typedef __attribute__((ext_vector_type(4))) float f32x4;

__device__ __forceinline__ unsigned short f2b(float f) {
  __hip_bfloat16 h = __float2bfloat16(f);
  return *reinterpret_cast<unsigned short*>(&h);
}
__device__ __forceinline__ float bu2f(unsigned u16) {  // low 16 bits = bf16
  union { unsigned u; float f; } c;
  c.u = u16 << 16;
  return c.f;
}
// tanh-form gelu via v_exp/v_rcp (max abs dev from exact erf-gelu ~3e-4).
__device__ __forceinline__ float gelu_f(float x) {
  float x2 = x * x;
  float t = 1.5957691216057308f * x * fmaf(0.044715f, x2, 1.0f);
  return x * __builtin_amdgcn_rcpf(1.0f + __expf(-t));
}

// ---- LDS staging helpers (R1-verified pattern) ---------------------------
// Tiles: N rows x 128 bf16 cols (256B rows), XOR swizzle byte^=((row&7)<<4).
__device__ __forceinline__ void stage_f32(unsigned char* dst, const float* __restrict__ src,
                                          int ld, int tid, int nch, int nthr) {
  for (int c = tid; c < nch; c += nthr) {
    int row = c >> 4, kc = c & 15;
    const float* s = src + row * ld + kc * 8;
    float4 u = *(const float4*)(s);
    float4 v = *(const float4*)(s + 4);
    union { unsigned short h[8]; uint4 q; } pk;
    pk.h[0] = f2b(u.x); pk.h[1] = f2b(u.y); pk.h[2] = f2b(u.z); pk.h[3] = f2b(u.w);
    pk.h[4] = f2b(v.x); pk.h[5] = f2b(v.y); pk.h[6] = f2b(v.z); pk.h[7] = f2b(v.w);
    *(uint4*)(dst + row * 256 + ((kc * 16) ^ ((row & 7) << 4))) = pk.q;
  }
}

__device__ __forceinline__ void stage_bf16(unsigned char* dst, const unsigned short* __restrict__ src,
                                           int tid, int nch, int nthr) {
  for (int c = tid; c < nch; c += nthr) {
    int row = c >> 4, kc = c & 15;
    uint4 q = *(const uint4*)(src + row * 128 + kc * 8);
    *(uint4*)(dst + row * 256 + ((kc * 16) ^ ((row & 7) << 4))) = q;
  }
}

// ---- MFMA tile GEMMs (R1-verified fragment mapping) ----------------------
// D layout (16x16x32 bf16): col = lane&15, row = (lane>>4)*4 + r

// 128x128 tile, 8 waves: wm in {0,1}, wn in {0..3} (k_tmp)
__device__ __forceinline__ void gemm_tile(const unsigned char* Ar, const unsigned char* Br,
                                          int lane, int wm, int wn, f32x4 acc[4][2]) {
  const int lr = lane & 15, lk = lane >> 4;
#pragma unroll
  for (int ks = 0; ks < 4; ++ks) {
    const int kb = ks * 64 + lk * 16;
    bf16x8 a[4], bb[2];
#pragma unroll
    for (int mf = 0; mf < 4; ++mf) {
      int m = wm * 64 + mf * 16 + lr;
      a[mf] = *(const bf16x8*)(Ar + m * 256 + (kb ^ ((m & 7) << 4)));
    }
#pragma unroll
    for (int nf = 0; nf < 2; ++nf) {
      int n = wn * 32 + nf * 16 + lr;
      bb[nf] = *(const bf16x8*)(Br + n * 256 + (kb ^ ((n & 7) << 4)));
    }
#pragma unroll
    for (int mf = 0; mf < 4; ++mf)
#pragma unroll
      for (int nf = 0; nf < 2; ++nf)
        acc[mf][nf] = __builtin_amdgcn_mfma_f32_16x16x32_bf16(a[mf], bb[nf], acc[mf][nf], 0, 0, 0);
  }
}

// 64x128 tile split over 8 waves: wave wn in {0..7} owns cols wn*16..+15.
__device__ __forceinline__ void gemm64x16(const unsigned char* Ar, const unsigned char* Br,
                                          int lane, int wn, f32x4 acc[4]) {
  const int lr = lane & 15, lk = lane >> 4;
#pragma unroll
  for (int ks = 0; ks < 4; ++ks) {
    const int kb = ks * 64 + lk * 16;
    bf16x8 a[4], bb;
#pragma unroll
    for (int mf = 0; mf < 4; ++mf) {
      int m = mf * 16 + lr;
      a[mf] = *(const bf16x8*)(Ar + m * 256 + (kb ^ ((m & 7) << 4)));
    }
    {
      int n = wn * 16 + lr;
      bb = *(const bf16x8*)(Br + n * 256 + (kb ^ ((n & 7) << 4)));
    }
#pragma unroll
    for (int mf = 0; mf < 4; ++mf)
      acc[mf] = __builtin_amdgcn_mfma_f32_16x16x32_bf16(a[mf], bb, acc[mf], 0, 0, 0);
  }
}

__device__ __forceinline__ void zero_acc8(f32x4 acc[4][2]) {
#pragma unroll
  for (int mf = 0; mf < 4; ++mf)
#pragma unroll
    for (int nf = 0; nf < 2; ++nf)
#pragma unroll
      for (int r = 0; r < 4; ++r) acc[mf][nf][r] = 0.0f;
}
__device__ __forceinline__ void zero_acc4(f32x4 acc[4]) {
#pragma unroll
  for (int mf = 0; mf < 4; ++mf)
#pragma unroll
    for (int r = 0; r < 4; ++r) acc[mf][r] = 0.0f;
}

// ---- rowwise linear: out[r][h] = sum_k in[r][k]*W[h][k] + b0[h]+b1[h]+b2[h]
__global__ __launch_bounds__(128) void rowlin_kernel(const float* __restrict__ in,
                                                     const float* __restrict__ W,
                                                     const float* __restrict__ b0,
                                                     const float* __restrict__ b1,
                                                     const float* __restrict__ b2,
                                                     float* __restrict__ out) {
  int r = blockIdx.x, h = threadIdx.x;
  __shared__ float xr[128];
  xr[h] = in[r * 128 + h];
  __syncthreads();
  const float* w = W + h * 128;
  float a = b0[h] + b1[h] + b2[h];
#pragma unroll 4
  for (int k = 0; k < 128; ++k) a = fmaf(xr[k], w[k], a);
  out[r * 128 + h] = a;
}

// ---- prep: 5 weight tiles -> plain bf16 row-major [128][128] -------------
__global__ __launch_bounds__(256) void k_prep_cvt(
    const float* __restrict__ res_w1, const float* __restrict__ res_w2,
    const float* __restrict__ pos_w1, const float* __restrict__ ex_w1,
    unsigned short* __restrict__ wTb) {
  const int blk = blockIdx.x;
  const float* src; const float* src2 = nullptr;
  if (blk == 0)      src = res_w1;
  else if (blk == 1) src = res_w2;
  else if (blk == 2) src = res_w1 + 16384;
  else if (blk == 3) src = res_w2 + 16384;
  else               { src = pos_w1; src2 = ex_w1; }
  unsigned short* dst = wTb + blk * 16384;
  for (int c = threadIdx.x; c < 2048; c += 256) {
    const int row = c >> 4, kc = c & 15;
    const float* s = (src2 && row >= 64) ? (src2 + (row - 64) * 128 + kc * 8)
                                         : (src + row * 128 + kc * 8);
    float4 u = *(const float4*)s;
    float4 v = *(const float4*)(s + 4);
    union { unsigned short h[8]; uint4 q; } pk;
    pk.h[0]=f2b(u.x); pk.h[1]=f2b(u.y); pk.h[2]=f2b(u.z); pk.h[3]=f2b(u.w);
    pk.h[4]=f2b(v.x); pk.h[5]=f2b(v.y); pk.h[6]=f2b(v.z); pk.h[7]=f2b(v.w);
    *(uint4*)(dst + row * 128 + kc * 8) = pk.q;
  }
}

// ---- k_tmp: tmp[bd][h][j] = sum_i be[bd][i]*W_bil[h][i][j] + W_tr[h][j] --
struct SMemTmp {
  unsigned char A[32768];   // be tile [m=bd][k=i] swz; reused as C staging
  unsigned char Bt[32768];  // W_bil[h]^T [n=j][k=i] swz
};

__global__ __launch_bounds__(512, 2) void k_tmp(const float* __restrict__ be,
                                                const float* __restrict__ Wb,
                                                const float* __restrict__ W_tr,
                                                unsigned short* __restrict__ tmp) {
  __shared__ SMemTmp sm;
  const int h = blockIdx.x >> 3, bd0 = (blockIdx.x & 7) << 7;
  const int tid = threadIdx.x, lane = tid & 63, w = tid >> 6, wm = w >> 2, wn = w & 3;
  const int lr = lane & 15, lk = lane >> 4;

  stage_f32(sm.A, be + bd0 * 128, 128, tid, 2048, 512);
  {  // transpose-stage W_bil[h]: (i,j) -> Bt[j][i]
    const float* src = Wb + h * 16384;
    for (int it = tid; it < 4096; it += 512) {
      int i = it >> 5, j0 = (it & 31) * 4;
      float4 u = *(const float4*)(src + i * 128 + j0);
      float vv[4] = {u.x, u.y, u.z, u.w};
#pragma unroll
      for (int e = 0; e < 4; ++e) {
        int j = j0 + e;
        *(unsigned short*)(sm.Bt + j * 256 + ((2 * i) ^ ((j & 7) << 4))) = f2b(vv[e]);
      }
    }
  }
  __syncthreads();
  f32x4 acc[4][2];
  zero_acc8(acc);
  gemm_tile(sm.A, sm.Bt, lane, wm, wn, acc);
  __syncthreads();  // all waves done reading sm.A -> safe to reuse as C staging
  float wtrv[2];
#pragma unroll
  for (int nf = 0; nf < 2; ++nf)
    wtrv[nf] = W_tr[h * 128 + wn * 32 + nf * 16 + lr];
#pragma unroll
  for (int mf = 0; mf < 4; ++mf)
#pragma unroll
    for (int nf = 0; nf < 2; ++nf)
#pragma unroll
      for (int r = 0; r < 4; ++r) {
        int row = wm * 64 + mf * 16 + lk * 4 + r;
        int col = wn * 32 + nf * 16 + lr;
        *(unsigned short*)(sm.A + row * 256 + col * 2) = f2b(acc[mf][nf][r] + wtrv[nf]);
      }
  __syncthreads();
  {  // coalesced copy-out: tmp[(bd0+row)*16384 + h*128 + j]
    int row = tid >> 2, part = tid & 3;
    const uint4* s = (const uint4*)(sm.A + row * 256 + part * 64);
    uint4* g = (uint4*)(tmp + (size_t)(bd0 + row) * 16384 + h * 128 + part * 32);
    g[0] = s[0]; g[1] = s[1]; g[2] = s[2]; g[3] = s[3];
  }
}

// ---- main fused kernel: 512 thr / 8 waves, 64 t-rows x 128 h, 54 KB LDS --
// Wave wn owns cols wn*16..+15; acc[4] (16 regs) + xp[4][2] (8 regs).
struct SMemMain {
  unsigned char A[16384];   // fused / h1 (bf16 swz, 64 rows)
  unsigned char Bm[32768];  // current weight / tmp tile (bf16 swz, [n][k])
  float ssum[64 * 8];
  float ssq[64 * 8];
  float part[2][64][4];
};

// LayerNorm (64 rows, 8 col-groups): x from acc+addv(+xp residual); stats via
// 16-lane shfl + 8-partial LDS combine; writes bf16 to Adst and packs xp.
template <bool USE_XP>
__device__ __forceinline__ void ln8(const f32x4 (&acc)[4], unsigned (&xp)[4][2],
                                    float addv, float* ssum, float* ssq,
                                    int lane, int wn,
                                    const float* __restrict__ g, const float* __restrict__ be,
                                    unsigned char* Adst) {
  const int lr = lane & 15, lk = lane >> 4;
  float x[4][4];
#pragma unroll
  for (int mf = 0; mf < 4; ++mf)
#pragma unroll
    for (int r = 0; r < 4; ++r) {
      float v = acc[mf][r] + addv;
      if (USE_XP) v += bu2f((xp[mf][r >> 1] >> (16 * (r & 1))) & 0xffffu);
      x[mf][r] = v;
    }
#pragma unroll
  for (int mf = 0; mf < 4; ++mf)
#pragma unroll
    for (int r = 0; r < 4; ++r) {
      float a = x[mf][r];
      float qq = a * a;
#pragma unroll
      for (int m = 1; m < 16; m <<= 1) { a += __shfl_xor(a, m); qq += __shfl_xor(qq, m); }
      if (lr == 0) {
        int row = mf * 16 + lk * 4 + r;
        ssum[row * 8 + wn] = a;
        ssq[row * 8 + wn] = qq;
      }
    }
  __syncthreads();
  const int col = wn * 16 + lr;
  const float gv = g[col], bev = be[col];
#pragma unroll
  for (int mf = 0; mf < 4; ++mf) {
    unsigned pk0 = 0;
#pragma unroll
    for (int r = 0; r < 4; ++r) {
      int row = mf * 16 + lk * 4 + r;
      const float* su = ssum + row * 8;
      const float* sq = ssq + row * 8;
      float sum = (su[0] + su[1]) + (su[2] + su[3]) + (su[4] + su[5]) + (su[6] + su[7]);
      float q2  = (sq[0] + sq[1]) + (sq[2] + sq[3]) + (sq[4] + sq[5]) + (sq[6] + sq[7]);
      float mean = sum * 0.0078125f;
      float var  = q2 * 0.0078125f - mean * mean;
      float rq = rsqrtf(var + 1e-5f);
      float y = (x[mf][r] - mean) * rq * gv + bev;
      unsigned short us = f2b(y);
      *(unsigned short*)(Adst + row * 256 + ((col * 2) ^ ((row & 7) << 4))) = us;
      if ((r & 1) == 0) pk0 = us;
      else xp[mf][r >> 1] = pk0 | ((unsigned)us << 16);
    }
  }
}

__global__ __launch_bounds__(512, 4) void k_main(
    const float* __restrict__ trunk, const unsigned short* __restrict__ tmp,
    const unsigned short* __restrict__ wTb,
    const float* __restrict__ br_all,
    const float* __restrict__ g_fn, const float* __restrict__ beta_fn,
    const float* __restrict__ res_b1, const float* __restrict__ res_b2,
    const float* __restrict__ res_g, const float* __restrict__ res_beta,
    const float* __restrict__ pos_b1, const float* __restrict__ pos_w2, const float* __restrict__ pos_b2,
    const float* __restrict__ ex_b1, const float* __restrict__ ex_w2, const float* __restrict__ ex_b2,
    const float* __restrict__ maskp, float* __restrict__ out) {
  __shared__ SMemMain sm;
  const int orig = blockIdx.x;
  const int gid = (orig & 7) * 512 + (orig >> 3);  // XCD swizzle, bijective (4096%8==0)
  const int bd = gid >> 2, qt = gid & 3;           // all 4 qt of a bd on one XCD
  const int b = bd >> 6, t0 = qt << 6;
  const int tid = threadIdx.x, lane = tid & 63, wn = tid >> 6;  // wn in 0..7
  const int lr = lane & 15, lk = lane >> 4;
  const int col = wn * 16 + lr;

  // ---- G1: fused0 = trunk_qt @ (tmp[b,d]+W_tr)^T ----
  stage_f32(sm.A, trunk + (size_t)(b * 256 + t0) * 128, 128, tid, 1024, 512);
  stage_bf16(sm.Bm, tmp + (size_t)bd * 16384, tid, 2048, 512);
  __syncthreads();                                       // bar 1
  f32x4 acc[4];
  zero_acc4(acc);
  gemm64x16(sm.A, sm.Bm, lane, wn, acc);

  // P0 LN: x = acc + (b_bil+b_tr+b_br+branchproj)[col]
  unsigned xp[4][2];
  {
    const float addv = br_all[bd * 128 + col];
    __syncthreads();  // all waves done with G1 reads of sm.A before LN overwrites it
    ln8<false>(acc, xp, addv, sm.ssum, sm.ssq, lane, wn, g_fn, beta_fn, sm.A);
  }

  // ---- residual blocks ----
  for (int i = 0; i < 2; ++i) {
    stage_bf16(sm.Bm, wTb + (i * 2) * 16384, tid, 2048, 512);  // res_w1[i]
    __syncthreads();                                     // bar: Bm staged + LN visible
    zero_acc4(acc);
    gemm64x16(sm.A, sm.Bm, lane, wn, acc);               // G2: fused @ w1[i]
    __syncthreads();                                     // bar: all done reading A
    {                                                    // h1 = gelu(D1+b1) -> sm.A
      float b1v = res_b1[i * 128 + col];
#pragma unroll
      for (int mf = 0; mf < 4; ++mf)
#pragma unroll
        for (int r = 0; r < 4; ++r) {
          int row = mf * 16 + lk * 4 + r;
          float hh = gelu_f(acc[mf][r] + b1v);
          *(unsigned short*)(sm.A + row * 256 + ((col * 2) ^ ((row & 7) << 4))) = f2b(hh);
        }
    }
    stage_bf16(sm.Bm, wTb + (i * 2 + 1) * 16384, tid, 2048, 512);  // res_w2[i]
    __syncthreads();                                     // bar: h1 + Bm staged
    zero_acc4(acc);
    gemm64x16(sm.A, sm.Bm, lane, wn, acc);               // G3: h1 @ w2[i]
    __syncthreads();                                     // bar: all done reading A
    {
      const float addv = res_b2[i * 128 + col];
      ln8<true>(acc, xp, addv, sm.ssum, sm.ssq, lane, wn,
                res_g + i * 128, res_beta + i * 128, sm.A);
    }
  }

  // ---- heads: D = fused @ [pos_w1; ex_w1]^T ----
  stage_bf16(sm.Bm, wTb + 4 * 16384, tid, 2048, 512);
  __syncthreads();
  zero_acc4(acc);
  gemm64x16(sm.A, sm.Bm, lane, wn, acc);

  // cols 0-63 (waves 0-3) = pos head, cols 64-127 (waves 4-7) = ex head
  {
    const int hc = (wn & 3) * 16 + lr;
    const float bias1 = (wn < 4) ? pos_b1[hc] : ex_b1[hc];
    const float w2v = (wn < 4) ? pos_w2[hc] : ex_w2[hc];
#pragma unroll
    for (int mf = 0; mf < 4; ++mf)
#pragma unroll
      for (int r = 0; r < 4; ++r) {
        float a = gelu_f(acc[mf][r] + bias1) * w2v;
#pragma unroll
        for (int m = 1; m < 16; m <<= 1) a += __shfl_xor(a, m);
        if (lr == 0) {
          int row = mf * 16 + lk * 4 + r;
          sm.part[wn >> 2][row][wn & 3] = a;
        }
      }
  }
  __syncthreads();
  if (tid < 128) {
    int row = tid >> 1, head = tid & 1;
    const float* p = sm.part[head][row];
    float v = (p[0] + p[1]) + (p[2] + p[3]);
    float mk = maskp[bd];
    int outr = bd * 256 + t0 + row;
    if (head == 0) {
      v += pos_b2[0];
      v = fminf(fmaxf(v, 0.0f), 1.0f);
      out[outr] = v * mk;
    } else {
      v += ex_b2[0];
      v = 1.0f / (1.0f + expf(-v));
      out[BDT_TOT + outr] = v * mk;
    }
  }
}

extern "C" void kernel_launch(void* const* d_in, const int* in_sizes, int n_in,
                              void* d_out, int out_size, void* d_ws, size_t ws_size,
                              hipStream_t stream) {
  const float* branch   = (const float*)d_in[0];
  const float* trunk    = (const float*)d_in[1];
  const float* mask     = (const float*)d_in[2];
  const float* W_bil    = (const float*)d_in[3];
  const float* b_bil    = (const float*)d_in[4];
  const float* W_br     = (const float*)d_in[5];
  const float* b_br     = (const float*)d_in[6];
  const float* W_tr     = (const float*)d_in[7];
  const float* b_tr     = (const float*)d_in[8];
  const float* g_fn     = (const float*)d_in[9];
  const float* beta_fn  = (const float*)d_in[10];
  const float* res_w1   = (const float*)d_in[11];
  const float* res_b1   = (const float*)d_in[12];
  const float* res_w2   = (const float*)d_in[13];
  const float* res_b2   = (const float*)d_in[14];
  const float* res_g    = (const float*)d_in[15];
  const float* res_beta = (const float*)d_in[16];
  const float* pos_w1   = (const float*)d_in[17];
  const float* pos_b1   = (const float*)d_in[18];
  const float* pos_w2   = (const float*)d_in[19];
  const float* pos_b2   = (const float*)d_in[20];
  const float* ex_w1    = (const float*)d_in[21];
  const float* ex_b1    = (const float*)d_in[22];
  const float* ex_w2    = (const float*)d_in[23];
  const float* ex_b2    = (const float*)d_in[24];
  float* out = (float*)d_out;

  // ws layout: 33.7 MB < proven 36.2 MB bound
  unsigned char* wsb = (unsigned char*)d_ws;
  unsigned short* tmp = (unsigned short*)wsb;              // 33,554,432 B
  float* br_all       = (float*)(wsb + 33554432);          //    524,288 B
  unsigned short* wTb = (unsigned short*)(wsb + 34078720); //    163,840 B

  hipLaunchKernelGGL(k_prep_cvt, dim3(5), dim3(256), 0, stream,
                     res_w1, res_w2, pos_w1, ex_w1, wTb);
  // br_all = branch @ W_br^T + (b_br + b_bil + b_tr)
  hipLaunchKernelGGL(rowlin_kernel, dim3(1024), dim3(128), 0, stream,
                     branch, W_br, b_br, b_bil, b_tr, br_all);
  hipLaunchKernelGGL(k_tmp, dim3(1024), dim3(512), 0, stream, branch, W_bil, W_tr, tmp);
  hipLaunchKernelGGL(k_main, dim3(4096), dim3(512), 0, stream,
                     trunk, tmp, wTb, br_all, g_fn, beta_fn,
                     res_b1, res_b2, res_g, res_beta,
                     pos_b1, pos_w2, pos_b2, ex_b1, ex_w2, ex_b2,
                     mask, out);
}

// Round 13
// 385.427 us; speedup vs baseline: 1.2863x; 1.2863x over previous
//
#include <hip/hip_runtime.h>
#include <hip/hip_bf16.h>

// Problem constants: B=16, D=64, T=256, BD=TD=H=128, H2=64, NRES=2
#define BDT_TOT 262144  // B*D*T

typedef __attribute__((ext_vector_type(8))) short bf16x8;
typedef __attribute__((ext_vector_type(4))) float f32x4;

__device__ __forceinline__ unsigned short f2b(float f) {
  __hip_bfloat16 h = __float2bfloat16(f);
  return *reinterpret_cast<unsigned short*>(&h);
}
__device__ __forceinline__ float bu2f(unsigned u16) {  // low 16 bits = bf16
  union { unsigned u; float f; } c;
  c.u = u16 << 16;
  return c.f;
}
// tanh-form gelu via v_exp/v_rcp (max abs dev from exact erf-gelu ~3e-4).
__device__ __forceinline__ float gelu_f(float x) {
  float x2 = x * x;
  float t = 1.5957691216057308f * x * fmaf(0.044715f, x2, 1.0f);
  return x * __builtin_amdgcn_rcpf(1.0f + __expf(-t));
}

// ---- LDS staging helpers (R1-verified pattern) ---------------------------
// Tiles: N rows x 128 bf16 cols (256B rows), XOR swizzle byte^=((row&7)<<4).
__device__ __forceinline__ void stage_f32(unsigned char* dst, const float* __restrict__ src,
                                          int ld, int tid, int nch, int nthr) {
  for (int c = tid; c < nch; c += nthr) {
    int row = c >> 4, kc = c & 15;
    const float* s = src + row * ld + kc * 8;
    float4 u = *(const float4*)(s);
    float4 v = *(const float4*)(s + 4);
    union { unsigned short h[8]; uint4 q; } pk;
    pk.h[0] = f2b(u.x); pk.h[1] = f2b(u.y); pk.h[2] = f2b(u.z); pk.h[3] = f2b(u.w);
    pk.h[4] = f2b(v.x); pk.h[5] = f2b(v.y); pk.h[6] = f2b(v.z); pk.h[7] = f2b(v.w);
    *(uint4*)(dst + row * 256 + ((kc * 16) ^ ((row & 7) << 4))) = pk.q;
  }
}

__device__ __forceinline__ void stage_bf16(unsigned char* dst, const unsigned short* __restrict__ src,
                                           int tid, int nch, int nthr) {
  for (int c = tid; c < nch; c += nthr) {
    int row = c >> 4, kc = c & 15;
    uint4 q = *(const uint4*)(src + row * 128 + kc * 8);
    *(uint4*)(dst + row * 256 + ((kc * 16) ^ ((row & 7) << 4))) = q;
  }
}

// ---- T14 async-stage: issue global loads early (regs), ds_write late -----
struct PF { uint4 v[8]; };  // 256 thr x 8 x 16B = one 128x128 bf16 tile

__device__ __forceinline__ void pf_load(PF& p, const unsigned short* __restrict__ src, int tid) {
#pragma unroll
  for (int k = 0; k < 8; ++k) {
    const int c = tid + k * 256;
    const int row = c >> 4, kc = c & 15;
    p.v[k] = *(const uint4*)(src + row * 128 + kc * 8);
  }
}
__device__ __forceinline__ void pf_store(const PF& p, unsigned char* dst, int tid) {
#pragma unroll
  for (int k = 0; k < 8; ++k) {
    const int c = tid + k * 256;
    const int row = c >> 4, kc = c & 15;
    *(uint4*)(dst + row * 256 + ((kc * 16) ^ ((row & 7) << 4))) = p.v[k];
  }
}

// ---- MFMA tile GEMMs (R1-verified fragment mapping) ----------------------
// D layout (16x16x32 bf16): col = lane&15, row = (lane>>4)*4 + r

// 128x128 tile, 8 waves: wm in {0,1}, wn in {0..3} (k_tmp)
__device__ __forceinline__ void gemm_tile(const unsigned char* Ar, const unsigned char* Br,
                                          int lane, int wm, int wn, f32x4 acc[4][2]) {
  const int lr = lane & 15, lk = lane >> 4;
#pragma unroll
  for (int ks = 0; ks < 4; ++ks) {
    const int kb = ks * 64 + lk * 16;
    bf16x8 a[4], bb[2];
#pragma unroll
    for (int mf = 0; mf < 4; ++mf) {
      int m = wm * 64 + mf * 16 + lr;
      a[mf] = *(const bf16x8*)(Ar + m * 256 + (kb ^ ((m & 7) << 4)));
    }
#pragma unroll
    for (int nf = 0; nf < 2; ++nf) {
      int n = wn * 32 + nf * 16 + lr;
      bb[nf] = *(const bf16x8*)(Br + n * 256 + (kb ^ ((n & 7) << 4)));
    }
#pragma unroll
    for (int mf = 0; mf < 4; ++mf)
#pragma unroll
      for (int nf = 0; nf < 2; ++nf)
        acc[mf][nf] = __builtin_amdgcn_mfma_f32_16x16x32_bf16(a[mf], bb[nf], acc[mf][nf], 0, 0, 0);
  }
}

// 64x128 tile, 4 waves: wave = wn in {0..3}, mf covers rows 0..63 (k_main)
__device__ __forceinline__ void gemm_tile64(const unsigned char* Ar, const unsigned char* Br,
                                            int lane, int wn, f32x4 acc[4][2]) {
  const int lr = lane & 15, lk = lane >> 4;
#pragma unroll
  for (int ks = 0; ks < 4; ++ks) {
    const int kb = ks * 64 + lk * 16;
    bf16x8 a[4], bb[2];
#pragma unroll
    for (int mf = 0; mf < 4; ++mf) {
      int m = mf * 16 + lr;
      a[mf] = *(const bf16x8*)(Ar + m * 256 + (kb ^ ((m & 7) << 4)));
    }
#pragma unroll
    for (int nf = 0; nf < 2; ++nf) {
      int n = wn * 32 + nf * 16 + lr;
      bb[nf] = *(const bf16x8*)(Br + n * 256 + (kb ^ ((n & 7) << 4)));
    }
#pragma unroll
    for (int mf = 0; mf < 4; ++mf)
#pragma unroll
      for (int nf = 0; nf < 2; ++nf)
        acc[mf][nf] = __builtin_amdgcn_mfma_f32_16x16x32_bf16(a[mf], bb[nf], acc[mf][nf], 0, 0, 0);
  }
}

__device__ __forceinline__ void zero_acc(f32x4 acc[4][2]) {
#pragma unroll
  for (int mf = 0; mf < 4; ++mf)
#pragma unroll
    for (int nf = 0; nf < 2; ++nf)
#pragma unroll
      for (int r = 0; r < 4; ++r) acc[mf][nf][r] = 0.0f;
}

// ---- rowwise linear: out[r][h] = sum_k in[r][k]*W[h][k] + b0[h]+b1[h]+b2[h]
__global__ __launch_bounds__(128) void rowlin_kernel(const float* __restrict__ in,
                                                     const float* __restrict__ W,
                                                     const float* __restrict__ b0,
                                                     const float* __restrict__ b1,
                                                     const float* __restrict__ b2,
                                                     float* __restrict__ out) {
  int r = blockIdx.x, h = threadIdx.x;
  __shared__ float xr[128];
  xr[h] = in[r * 128 + h];
  __syncthreads();
  const float* w = W + h * 128;
  float a = b0[h] + b1[h] + b2[h];
#pragma unroll 4
  for (int k = 0; k < 128; ++k) a = fmaf(xr[k], w[k], a);
  out[r * 128 + h] = a;
}

// ---- prep: 5 weight tiles -> plain bf16 row-major [128][128] -------------
__global__ __launch_bounds__(256) void k_prep_cvt(
    const float* __restrict__ res_w1, const float* __restrict__ res_w2,
    const float* __restrict__ pos_w1, const float* __restrict__ ex_w1,
    unsigned short* __restrict__ wTb) {
  const int blk = blockIdx.x;
  const float* src; const float* src2 = nullptr;
  if (blk == 0)      src = res_w1;
  else if (blk == 1) src = res_w2;
  else if (blk == 2) src = res_w1 + 16384;
  else if (blk == 3) src = res_w2 + 16384;
  else               { src = pos_w1; src2 = ex_w1; }
  unsigned short* dst = wTb + blk * 16384;
  for (int c = threadIdx.x; c < 2048; c += 256) {
    const int row = c >> 4, kc = c & 15;
    const float* s = (src2 && row >= 64) ? (src2 + (row - 64) * 128 + kc * 8)
                                         : (src + row * 128 + kc * 8);
    float4 u = *(const float4*)s;
    float4 v = *(const float4*)(s + 4);
    union { unsigned short h[8]; uint4 q; } pk;
    pk.h[0]=f2b(u.x); pk.h[1]=f2b(u.y); pk.h[2]=f2b(u.z); pk.h[3]=f2b(u.w);
    pk.h[4]=f2b(v.x); pk.h[5]=f2b(v.y); pk.h[6]=f2b(v.z); pk.h[7]=f2b(v.w);
    *(uint4*)(dst + row * 128 + kc * 8) = pk.q;
  }
}

// ---- k_tmp: tmp[bd][h][j] = sum_i be[bd][i]*W_bil[h][i][j] + W_tr[h][j] --
struct SMemTmp {
  unsigned char A[32768];   // be tile [m=bd][k=i] swz; reused as C staging
  unsigned char Bt[32768];  // W_bil[h]^T [n=j][k=i] swz
};

__global__ __launch_bounds__(512, 2) void k_tmp(const float* __restrict__ be,
                                                const float* __restrict__ Wb,
                                                const float* __restrict__ W_tr,
                                                unsigned short* __restrict__ tmp) {
  __shared__ SMemTmp sm;
  const int h = blockIdx.x >> 3, bd0 = (blockIdx.x & 7) << 7;
  const int tid = threadIdx.x, lane = tid & 63, w = tid >> 6, wm = w >> 2, wn = w & 3;
  const int lr = lane & 15, lk = lane >> 4;

  stage_f32(sm.A, be + bd0 * 128, 128, tid, 2048, 512);
  {  // transpose-stage W_bil[h]: (i,j) -> Bt[j][i]
    const float* src = Wb + h * 16384;
    for (int it = tid; it < 4096; it += 512) {
      int i = it >> 5, j0 = (it & 31) * 4;
      float4 u = *(const float4*)(src + i * 128 + j0);
      float vv[4] = {u.x, u.y, u.z, u.w};
#pragma unroll
      for (int e = 0; e < 4; ++e) {
        int j = j0 + e;
        *(unsigned short*)(sm.Bt + j * 256 + ((2 * i) ^ ((j & 7) << 4))) = f2b(vv[e]);
      }
    }
  }
  __syncthreads();
  f32x4 acc[4][2];
  zero_acc(acc);
  gemm_tile(sm.A, sm.Bt, lane, wm, wn, acc);
  __syncthreads();  // all waves done reading sm.A -> safe to reuse as C staging
  float wtrv[2];
#pragma unroll
  for (int nf = 0; nf < 2; ++nf)
    wtrv[nf] = W_tr[h * 128 + wn * 32 + nf * 16 + lr];
#pragma unroll
  for (int mf = 0; mf < 4; ++mf)
#pragma unroll
    for (int nf = 0; nf < 2; ++nf)
#pragma unroll
      for (int r = 0; r < 4; ++r) {
        int row = wm * 64 + mf * 16 + lk * 4 + r;
        int col = wn * 32 + nf * 16 + lr;
        *(unsigned short*)(sm.A + row * 256 + col * 2) = f2b(acc[mf][nf][r] + wtrv[nf]);
      }
  __syncthreads();
  {  // coalesced copy-out: tmp[(bd0+row)*16384 + h*128 + j]
    int row = tid >> 2, part = tid & 3;
    const uint4* s = (const uint4*)(sm.A + row * 256 + part * 64);
    uint4* g = (uint4*)(tmp + (size_t)(bd0 + row) * 16384 + h * 128 + part * 32);
    g[0] = s[0]; g[1] = s[1]; g[2] = s[2]; g[3] = s[3];
  }
}

// ---- main fused kernel: 256 thr / 4 waves, 64 t-rows x 128 h, 51 KB LDS --
struct SMemMain {
  unsigned char A[16384];   // fused / h1 (bf16 swz, 64 rows)
  unsigned char Bm[32768];  // current weight / tmp tile (bf16 swz, [n][k])
  float ssum[64 * 4];
  float ssq[64 * 4];
  float part[2][64][2];
};

// LayerNorm (64 rows): per-lane x[mf][nf][r] f32 -> bf16 into Adst AND packed xp.
__device__ __forceinline__ void ln_store64(float (&x)[4][2][4], unsigned (&xp)[4][4],
                                           float* ssum, float* ssq,
                                           int lane, int wn,
                                           const float* __restrict__ g, const float* __restrict__ be,
                                           unsigned char* Adst) {
  const int lr = lane & 15, lk = lane >> 4;
#pragma unroll
  for (int mf = 0; mf < 4; ++mf)
#pragma unroll
    for (int r = 0; r < 4; ++r) {
      float a = x[mf][0][r] + x[mf][1][r];
      float qq = x[mf][0][r] * x[mf][0][r] + x[mf][1][r] * x[mf][1][r];
#pragma unroll
      for (int m = 1; m < 16; m <<= 1) { a += __shfl_xor(a, m); qq += __shfl_xor(qq, m); }
      if (lr == 0) {
        int row = mf * 16 + lk * 4 + r;
        ssum[row * 4 + wn] = a;
        ssq[row * 4 + wn] = qq;
      }
    }
  __syncthreads();
  float gv[2], bv[2];
#pragma unroll
  for (int nf = 0; nf < 2; ++nf) {
    int col = wn * 32 + nf * 16 + lr;
    gv[nf] = g[col]; bv[nf] = be[col];
  }
#pragma unroll
  for (int mf = 0; mf < 4; ++mf)
#pragma unroll
    for (int r = 0; r < 4; ++r) {
      int row = mf * 16 + lk * 4 + r;
      float sum = ssum[row * 4 + 0] + ssum[row * 4 + 1] + ssum[row * 4 + 2] + ssum[row * 4 + 3];
      float sq  = ssq[row * 4 + 0] + ssq[row * 4 + 1] + ssq[row * 4 + 2] + ssq[row * 4 + 3];
      float mean = sum * 0.0078125f;
      float var  = sq * 0.0078125f - mean * mean;
      float rq = rsqrtf(var + 1e-5f);
      unsigned pk = 0;
#pragma unroll
      for (int nf = 0; nf < 2; ++nf) {
        int col = wn * 32 + nf * 16 + lr;
        float y = (x[mf][nf][r] - mean) * rq * gv[nf] + bv[nf];
        unsigned short us = f2b(y);
        pk |= ((unsigned)us) << (16 * nf);
        *(unsigned short*)(Adst + row * 256 + ((col * 2) ^ ((row & 7) << 4))) = us;
      }
      xp[mf][r] = pk;
    }
}

__global__ __launch_bounds__(256, 2) void k_main(
    const float* __restrict__ trunk, const unsigned short* __restrict__ tmp,
    const unsigned short* __restrict__ wTb,
    const float* __restrict__ br_all,
    const float* __restrict__ g_fn, const float* __restrict__ beta_fn,
    const float* __restrict__ res_b1, const float* __restrict__ res_b2,
    const float* __restrict__ res_g, const float* __restrict__ res_beta,
    const float* __restrict__ pos_b1, const float* __restrict__ pos_w2, const float* __restrict__ pos_b2,
    const float* __restrict__ ex_b1, const float* __restrict__ ex_w2, const float* __restrict__ ex_b2,
    const float* __restrict__ maskp, float* __restrict__ out) {
  __shared__ SMemMain sm;
  const int orig = blockIdx.x;
  const int gid = (orig & 7) * 512 + (orig >> 3);  // XCD swizzle, bijective (4096%8==0)
  const int bd = gid >> 2, qt = gid & 3;           // all 4 qt of a bd on one XCD
  const int b = bd >> 6, t0 = qt << 6;
  const int tid = threadIdx.x, lane = tid & 63, wn = tid >> 6;
  const int lr = lane & 15, lk = lane >> 4;

  // ---- G1: fused0 = trunk_qt @ (tmp[b,d]+W_tr)^T ----
  stage_f32(sm.A, trunk + (size_t)(b * 256 + t0) * 128, 128, tid, 1024, 256);
  stage_bf16(sm.Bm, tmp + (size_t)bd * 16384, tid, 2048, 256);
  __syncthreads();                                       // bar 1
  PF pf;
  pf_load(pf, wTb, tid);                                 // w1[0] loads in flight
  f32x4 acc[4][2];
  zero_acc(acc);
  gemm_tile64(sm.A, sm.Bm, lane, wn, acc);               // G1 (covers pf latency)

  // P0: x = acc + (b_bil+b_tr+b_br+branchproj)[h]
  unsigned xp[4][4];
  {
    float x[4][2][4];
#pragma unroll
    for (int nf = 0; nf < 2; ++nf) {
      int col = wn * 32 + nf * 16 + lr;
      float bb = br_all[bd * 128 + col];
#pragma unroll
      for (int mf = 0; mf < 4; ++mf)
#pragma unroll
        for (int r = 0; r < 4; ++r)
          x[mf][nf][r] = acc[mf][nf][r] + bb;
    }
    __syncthreads();                                     // bar 2: G1 reads of A & Bm done
    pf_store(pf, sm.Bm, tid);                            // write w1[0]
    pf_load(pf, wTb + 16384, tid);                       // w2[0] in flight (covered by LN stats)
    ln_store64(x, xp, sm.ssum, sm.ssq, lane, wn, g_fn, beta_fn, sm.A);  // stats bar inside
  }
  __syncthreads();                                       // bar: Bm(w1[0]) + A(LN) ready

  // ---- residual blocks ----
  for (int i = 0; i < 2; ++i) {
    zero_acc(acc);
    gemm_tile64(sm.A, sm.Bm, lane, wn, acc);             // G2: fused @ w1[i]
    __syncthreads();                                     // bar: all done reading A & Bm
    pf_store(pf, sm.Bm, tid);                            // write w2[i]
    pf_load(pf, wTb + (i == 0 ? 2 : 4) * 16384, tid);    // w1[1] / heads in flight
#pragma unroll
    for (int nf = 0; nf < 2; ++nf) {                     // h1 = gelu(D1+b1) -> sm.A
      int col = wn * 32 + nf * 16 + lr;
      float b1v = res_b1[i * 128 + col];
#pragma unroll
      for (int mf = 0; mf < 4; ++mf)
#pragma unroll
        for (int r = 0; r < 4; ++r) {
          int row = mf * 16 + lk * 4 + r;
          float hh = gelu_f(acc[mf][nf][r] + b1v);
          *(unsigned short*)(sm.A + row * 256 + ((col * 2) ^ ((row & 7) << 4))) = f2b(hh);
        }
    }
    __syncthreads();                                     // bar: h1 + Bm(w2[i]) ready
    zero_acc(acc);
    gemm_tile64(sm.A, sm.Bm, lane, wn, acc);             // G3: h1 @ w2[i]
    __syncthreads();                                     // bar: all done reading A & Bm
    pf_store(pf, sm.Bm, tid);                            // write w1[1] / heads
    if (i == 0) pf_load(pf, wTb + 3 * 16384, tid);       // w2[1] in flight
    {
      float x[4][2][4];
#pragma unroll
      for (int nf = 0; nf < 2; ++nf) {                   // residual from packed regs
        int col = wn * 32 + nf * 16 + lr;
        float b2v = res_b2[i * 128 + col];
#pragma unroll
        for (int mf = 0; mf < 4; ++mf)
#pragma unroll
          for (int r = 0; r < 4; ++r)
            x[mf][nf][r] = bu2f((xp[mf][r] >> (16 * nf)) & 0xffffu) + acc[mf][nf][r] + b2v;
      }
      ln_store64(x, xp, sm.ssum, sm.ssq, lane, wn,
                 res_g + i * 128, res_beta + i * 128, sm.A);  // stats bar inside
    }
    __syncthreads();                                     // bar: Bm(next) + A(LN) ready
  }

  // ---- heads: D = fused @ [pos_w1; ex_w1]^T  (Bm already holds heads) ----
  zero_acc(acc);
  gemm_tile64(sm.A, sm.Bm, lane, wn, acc);

  float s3[4][4];
#pragma unroll
  for (int mf = 0; mf < 4; ++mf)
#pragma unroll
    for (int r = 0; r < 4; ++r) s3[mf][r] = 0.0f;
#pragma unroll
  for (int nf = 0; nf < 2; ++nf) {
    int col = wn * 32 + nf * 16 + lr;
    float bias1 = (col < 64) ? pos_b1[col] : ex_b1[col - 64];
    float w2v = (col < 64) ? pos_w2[col] : ex_w2[col - 64];
#pragma unroll
    for (int mf = 0; mf < 4; ++mf)
#pragma unroll
      for (int r = 0; r < 4; ++r)
        s3[mf][r] += gelu_f(acc[mf][nf][r] + bias1) * w2v;
  }
#pragma unroll
  for (int mf = 0; mf < 4; ++mf)
#pragma unroll
    for (int r = 0; r < 4; ++r) {
      float a = s3[mf][r];
#pragma unroll
      for (int m = 1; m < 16; m <<= 1) a += __shfl_xor(a, m);
      s3[mf][r] = a;
    }
  if (lr == 0) {
#pragma unroll
    for (int mf = 0; mf < 4; ++mf)
#pragma unroll
      for (int r = 0; r < 4; ++r) {
        int row = mf * 16 + lk * 4 + r;
        sm.part[wn >> 1][row][wn & 1] = s3[mf][r];
      }
  }
  __syncthreads();
  if (tid < 128) {
    int row = tid >> 1, head = tid & 1;
    float v = sm.part[head][row][0] + sm.part[head][row][1];
    float mk = maskp[bd];
    int outr = bd * 256 + t0 + row;
    if (head == 0) {
      v += pos_b2[0];
      v = fminf(fmaxf(v, 0.0f), 1.0f);
      out[outr] = v * mk;
    } else {
      v += ex_b2[0];
      v = 1.0f / (1.0f + expf(-v));
      out[BDT_TOT + outr] = v * mk;
    }
  }
}

extern "C" void kernel_launch(void* const* d_in, const int* in_sizes, int n_in,
                              void* d_out, int out_size, void* d_ws, size_t ws_size,
                              hipStream_t stream) {
  const float* branch   = (const float*)d_in[0];
  const float* trunk    = (const float*)d_in[1];
  const float* mask     = (const float*)d_in[2];
  const float* W_bil    = (const float*)d_in[3];
  const float* b_bil    = (const float*)d_in[4];
  const float* W_br     = (const float*)d_in[5];
  const float* b_br     = (const float*)d_in[6];
  const float* W_tr     = (const float*)d_in[7];
  const float* b_tr     = (const float*)d_in[8];
  const float* g_fn     = (const float*)d_in[9];
  const float* beta_fn  = (const float*)d_in[10];
  const float* res_w1   = (const float*)d_in[11];
  const float* res_b1   = (const float*)d_in[12];
  const float* res_w2   = (const float*)d_in[13];
  const float* res_b2   = (const float*)d_in[14];
  const float* res_g    = (const float*)d_in[15];
  const float* res_beta = (const float*)d_in[16];
  const float* pos_w1   = (const float*)d_in[17];
  const float* pos_b1   = (const float*)d_in[18];
  const float* pos_w2   = (const float*)d_in[19];
  const float* pos_b2   = (const float*)d_in[20];
  const float* ex_w1    = (const float*)d_in[21];
  const float* ex_b1    = (const float*)d_in[22];
  const float* ex_w2    = (const float*)d_in[23];
  const float* ex_b2    = (const float*)d_in[24];
  float* out = (float*)d_out;

  // ws layout: 33.7 MB < proven 36.2 MB bound
  unsigned char* wsb = (unsigned char*)d_ws;
  unsigned short* tmp = (unsigned short*)wsb;              // 33,554,432 B
  float* br_all       = (float*)(wsb + 33554432);          //    524,288 B
  unsigned short* wTb = (unsigned short*)(wsb + 34078720); //    163,840 B

  hipLaunchKernelGGL(k_prep_cvt, dim3(5), dim3(256), 0, stream,
                     res_w1, res_w2, pos_w1, ex_w1, wTb);
  // br_all = branch @ W_br^T + (b_br + b_bil + b_tr)
  hipLaunchKernelGGL(rowlin_kernel, dim3(1024), dim3(128), 0, stream,
                     branch, W_br, b_br, b_bil, b_tr, br_all);
  hipLaunchKernelGGL(k_tmp, dim3(1024), dim3(512), 0, stream, branch, W_bil, W_tr, tmp);
  hipLaunchKernelGGL(k_main, dim3(4096), dim3(256), 0, stream,
                     trunk, tmp, wTb, br_all, g_fn, beta_fn,
                     res_b1, res_b2, res_g, res_beta,
                     pos_b1, pos_w2, pos_b2, ex_b1, ex_w2, ex_b2,
                     mask, out);
}